// Round 1
// baseline (900.621 us; speedup 1.0000x reference)
//
#include <hip/hip_runtime.h>

// Problem constants (from reference): B=256, C=512, H=W=28, NCLS=20
#define BATCH 256
#define CH    512
#define HW    784          // 28*28
#define HW4   196          // 784/4 float4s per (b,c) row
#define NCLS  20

// Kernel 1: one block per (b,c) row.
//  - reweight scalar rw = sum_k label[b,k] * W[k,c]   (wave-uniform, ~free)
//  - stream row: pooled-sum of x, write fmap*rw to out_map  (float4)
//  - block-reduce pooled sum -> pooled[b*CH+c] (in workspace)
__global__ __launch_bounds__(128) void fused_pool_mul(
    const float* __restrict__ x, const float* __restrict__ fmap,
    const int*   __restrict__ label, const float* __restrict__ W,
    float* __restrict__ pooled, float* __restrict__ out_map)
{
    const int bid = blockIdx.x;        // 0 .. BATCH*CH-1
    const int b   = bid >> 9;          // / 512
    const int c   = bid & 511;         // % 512
    const int tid = threadIdx.x;

    // Per-row reweight scalar (block-uniform -> scalar unit, L1-resident tables)
    float rw = 0.0f;
#pragma unroll
    for (int k = 0; k < NCLS; ++k)
        rw += (float)label[b * NCLS + k] * W[k * CH + c];

    const long long base = (long long)bid * HW;
    const float4* x4 = (const float4*)(x    + base);
    const float4* f4 = (const float4*)(fmap + base);
    float4*       o4 = (float4*)(out_map + base);

    float s = 0.0f;
#pragma unroll
    for (int j = tid; j < HW4; j += 128) {   // j = tid, tid+128 (tid<68)
        float4 xv = x4[j];
        s += (xv.x + xv.y) + (xv.z + xv.w);
        float4 fv = f4[j];
        float4 ov;
        ov.x = fv.x * rw; ov.y = fv.y * rw; ov.z = fv.z * rw; ov.w = fv.w * rw;
        o4[j] = ov;
    }

    // Reduce s across 128 threads (2 waves)
#pragma unroll
    for (int off = 32; off > 0; off >>= 1)
        s += __shfl_down(s, off, 64);
    __shared__ float partial[2];
    if ((tid & 63) == 0) partial[tid >> 6] = s;
    __syncthreads();
    if (tid == 0)
        pooled[bid] = (partial[0] + partial[1]) * (1.0f / (float)HW);
}

// Kernel 2: logits[b,n] = dot(pooled[b,:], W[n,:]) + bias[n]
// One 64-lane wave per batch row; pooled row held in 8 regs/lane.
__global__ __launch_bounds__(64) void logits_kernel(
    const float* __restrict__ pooled, const float* __restrict__ W,
    const float* __restrict__ bias, float* __restrict__ logits)
{
    const int b    = blockIdx.x;
    const int lane = threadIdx.x;

    float p[8];
#pragma unroll
    for (int i = 0; i < 8; ++i)
        p[i] = pooled[b * CH + lane + i * 64];

    for (int n = 0; n < NCLS; ++n) {
        float s = 0.0f;
#pragma unroll
        for (int i = 0; i < 8; ++i)
            s += p[i] * W[n * CH + lane + i * 64];
#pragma unroll
        for (int off = 32; off > 0; off >>= 1)
            s += __shfl_down(s, off, 64);
        if (lane == 0)
            logits[b * NCLS + n] = s + bias[n];
    }
}

extern "C" void kernel_launch(void* const* d_in, const int* in_sizes, int n_in,
                              void* d_out, int out_size, void* d_ws, size_t ws_size,
                              hipStream_t stream) {
    const float* x     = (const float*)d_in[0];   // [256,512,28,28]
    const float* fmap  = (const float*)d_in[1];   // [256,512,28,28]
    const int*   label = (const int*)  d_in[2];   // [256,20]
    const float* W     = (const float*)d_in[3];   // [20,512]
    const float* bias  = (const float*)d_in[4];   // [20]

    float* logits  = (float*)d_out;                    // [256,20]
    float* out_map = (float*)d_out + BATCH * NCLS;     // [256,512,28,28]
    float* pooled  = (float*)d_ws;                     // [256,512] = 512 KB scratch

    fused_pool_mul<<<BATCH * CH, 128, 0, stream>>>(x, fmap, label, W, pooled, out_map);
    logits_kernel<<<BATCH, 64, 0, stream>>>(pooled, W, bias, logits);
}